// Round 1
// baseline (448.837 us; speedup 1.0000x reference)
//
#include <hip/hip_runtime.h>
#include <hip/hip_bf16.h>

typedef __attribute__((ext_vector_type(4))) float floatx4;
typedef __attribute__((ext_vector_type(8))) short shortx8;

#define HW   1024
#define C    128
#define EPS  1e-8f

// Kernel 1: normalize over channel dim + transpose to fnT[view][p][c] (bf16)
// x: [32 views][128 c][1024 p] fp32.  fnT: [32][1024][128] bf16 (8 MB in d_ws)
__global__ __launch_bounds__(256) void norm_transpose(const float* __restrict__ x,
                                                      __hip_bfloat16* __restrict__ fnT) {
    int g = blockIdx.x * 256 + threadIdx.x;   // g in [0, 32*1024)
    int v = g >> 10;
    int p = g & 1023;
    const float* xv = x + (size_t)v * (C * HW) + p;
    float s = 0.f;
#pragma unroll
    for (int c = 0; c < C; ++c) {
        float val = xv[(size_t)c * HW];      // coalesced: lanes = consecutive p
        s += val * val;
    }
    float scale = 1.0f / (sqrtf(s) + EPS);
    __hip_bfloat16* dst = fnT + (size_t)g * C;
#pragma unroll
    for (int c0 = 0; c0 < C; c0 += 8) {
        shortx8 pack;
#pragma unroll
        for (int u = 0; u < 8; ++u) {
            __hip_bfloat16 h = __float2bfloat16(xv[(size_t)(c0 + u) * HW] * scale);
            pack[u] = *(short*)&h;
        }
        *(shortx8*)(dst + c0) = pack;        // 16B store per thread
    }
}

// Kernel 2: 96 GEMMs C[p,q] = sum_c fnT[vA][p][c] * fnT[vB][q][c]
// grid (8 qtile, 8 ptile, 96 g), block 256 = 4 waves; wave -> 64x64 subtile
__global__ __launch_bounds__(256) void corr_gemm(const __hip_bfloat16* __restrict__ fnT,
                                                 float* __restrict__ out) {
    int g = blockIdx.z;          // (b*4 + i)*3 + k
    int b = g / 12;
    int r = g % 12;
    int i = r / 3;
    int k = r % 3;
    int j = k + (k >= i);        // jj[i][k]
    int vA = b * 4 + j;          // provides p (rows)
    int vB = b * 4 + i;          // provides q (cols)

    int lane = threadIdx.x & 63;
    int wave = threadIdx.x >> 6;
    int p0 = blockIdx.y * 128 + (wave >> 1) * 64;
    int q0 = blockIdx.x * 128 + (wave & 1) * 64;
    int lr   = lane & 15;        // row within 16 (operand layout)
    int quad = lane >> 4;        // 0..3

    const __hip_bfloat16* Abase = fnT + (size_t)vA * (HW * C) + (size_t)(p0 + lr) * C + quad * 8;
    const __hip_bfloat16* Bbase = fnT + (size_t)vB * (HW * C) + (size_t)(q0 + lr) * C + quad * 8;

    floatx4 acc[4][4] = {};

#pragma unroll
    for (int kk = 0; kk < 4; ++kk) {         // K = 128 in 4 steps of 32
        int co = kk * 32;
        shortx8 a[4], bfr[4];
#pragma unroll
        for (int t = 0; t < 4; ++t) {
            a[t]   = *(const shortx8*)(Abase + (size_t)t * 16 * C + co);
            bfr[t] = *(const shortx8*)(Bbase + (size_t)t * 16 * C + co);
        }
#pragma unroll
        for (int mt = 0; mt < 4; ++mt)
#pragma unroll
            for (int nt = 0; nt < 4; ++nt)
                acc[mt][nt] = __builtin_amdgcn_mfma_f32_16x16x32_bf16(a[mt], bfr[nt], acc[mt][nt], 0, 0, 0);
    }

    // Epilogue: D layout col=lane&15, row=quad*4+reg
    float* outg = out + (size_t)g * HW * HW;
#pragma unroll
    for (int mt = 0; mt < 4; ++mt) {
#pragma unroll
        for (int rr = 0; rr < 4; ++rr) {
            int row = p0 + mt * 16 + quad * 4 + rr;
            float* orow = outg + (size_t)row * HW + q0 + lr;
#pragma unroll
            for (int nt = 0; nt < 4; ++nt)
                orow[nt * 16] = acc[mt][nt][rr];   // 64B contiguous per quarter-wave
        }
    }
}

extern "C" void kernel_launch(void* const* d_in, const int* in_sizes, int n_in,
                              void* d_out, int out_size, void* d_ws, size_t ws_size,
                              hipStream_t stream) {
    const float* x = (const float*)d_in[0];
    float* out = (float*)d_out;
    __hip_bfloat16* fnT = (__hip_bfloat16*)d_ws;   // 32*1024*128*2 = 8 MB

    norm_transpose<<<dim3(32 * 1024 / 256), 256, 0, stream>>>(x, fnT);
    corr_gemm<<<dim3(8, 8, 96), 256, 0, stream>>>(fnT, out);
}

// Round 2
// 410.329 us; speedup vs baseline: 1.0938x; 1.0938x over previous
//
#include <hip/hip_runtime.h>
#include <hip/hip_bf16.h>

typedef __attribute__((ext_vector_type(4))) float floatx4;
typedef __attribute__((ext_vector_type(8))) short shortx8;

#define HW   1024
#define C    128
#define EPS  1e-8f

// Kernel 1: normalize over channel dim + transpose to fnT[view][p][c] (bf16)
// x: [32 views][128 c][1024 p] fp32.  fnT: [32][1024][128] bf16 (8 MB in d_ws)
__global__ __launch_bounds__(256) void norm_transpose(const float* __restrict__ x,
                                                      __hip_bfloat16* __restrict__ fnT) {
    int g = blockIdx.x * 256 + threadIdx.x;   // g in [0, 32*1024)
    int v = g >> 10;
    int p = g & 1023;
    const float* xv = x + (size_t)v * (C * HW) + p;
    float s = 0.f;
#pragma unroll
    for (int c = 0; c < C; ++c) {
        float val = xv[(size_t)c * HW];      // coalesced: lanes = consecutive p
        s += val * val;
    }
    float scale = 1.0f / (sqrtf(s) + EPS);
    __hip_bfloat16* dst = fnT + (size_t)g * C;
#pragma unroll
    for (int c0 = 0; c0 < C; c0 += 8) {
        shortx8 pack;
#pragma unroll
        for (int u = 0; u < 8; ++u) {
            __hip_bfloat16 h = __float2bfloat16(xv[(size_t)(c0 + u) * HW] * scale);
            pack[u] = *(short*)&h;
        }
        *(shortx8*)(dst + c0) = pack;        // 16B store per thread
    }
}

// Kernel 2: 96 GEMMs C[p,q] = sum_c fnT[vA][p][c] * fnT[vB][q][c]
// m97-style: one-shot K=128 LDS staging via global_load_lds(16B),
// XOR-chunk-swizzled LDS layout (global_load_lds forbids padding; row stride
// 256 B is bank-aligned, so unswizzled b128 reads would be ~8-way conflicted).
// LDS 16B-chunk slot (row, c) holds global chunk (row, c ^ (row&15)).
__global__ __launch_bounds__(256, 2) void corr_gemm(const __hip_bfloat16* __restrict__ fnT,
                                                    float* __restrict__ out) {
    __shared__ __hip_bfloat16 Atile[128 * 128];   // 32 KB
    __shared__ __hip_bfloat16 Btile[128 * 128];   // 32 KB

    int g = blockIdx.z;          // (b*4 + i)*3 + k
    int b = g / 12;
    int r = g % 12;
    int i = r / 3;
    int k = r % 3;
    int j = k + (k >= i);        // jj[i][k]
    int vA = b * 4 + j;          // provides p (rows)
    int vB = b * 4 + i;          // provides q (cols)

    int lane = threadIdx.x & 63;
    int wave = threadIdx.x >> 6;
    int p0 = blockIdx.y * 128;
    int q0 = blockIdx.x * 128;

    // --- Stage: A/B tiles are contiguous 32 KB slabs of fnT ---
    const char* Ag = (const char*)(fnT + ((size_t)vA * HW + p0) * C);
    const char* Bg = (const char*)(fnT + ((size_t)vB * HW + q0) * C);
    char* Alds = (char*)&Atile[0];
    char* Blds = (char*)&Btile[0];
#pragma unroll
    for (int t = 0; t < 8; ++t) {
        int s = (wave * 8 + t) * 64 + lane;          // chunk slot 0..2047
        int row = s >> 4;
        int c16 = s & 15;
        int goff = (row * 16 + (c16 ^ (row & 15))) * 16;
        int loff = (wave * 8 + t) * 1024;            // wave-uniform LDS base
        __builtin_amdgcn_global_load_lds(
            (const __attribute__((address_space(1))) void*)(Ag + goff),
            (__attribute__((address_space(3))) void*)(Alds + loff), 16, 0, 0);
        __builtin_amdgcn_global_load_lds(
            (const __attribute__((address_space(1))) void*)(Bg + goff),
            (__attribute__((address_space(3))) void*)(Blds + loff), 16, 0, 0);
    }
    __syncthreads();   // compiler emits vmcnt(0) drain before s_barrier

    // --- Compute: wave -> 64x64 subtile, 4x4 grid of 16x16x32 MFMA ---
    int wp = (wave >> 1) * 64;
    int wq = (wave & 1) * 64;
    int lr   = lane & 15;
    int quad = lane >> 4;

    const char* Ab = (const char*)Atile + (size_t)(wp + lr) * 256;
    const char* Bb = (const char*)Btile + (size_t)(wq + lr) * 256;

    floatx4 acc[4][4] = {};

#pragma unroll
    for (int kk = 0; kk < 4; ++kk) {                 // K = 128 in 4 steps of 32
        int co = ((kk * 4 + quad) ^ lr) * 16;        // swizzled chunk offset (row&15 == lr)
        shortx8 a[4], bfr[4];
#pragma unroll
        for (int t = 0; t < 4; ++t) {
            a[t]   = *(const shortx8*)(Ab + t * 16 * 256 + co);
            bfr[t] = *(const shortx8*)(Bb + t * 16 * 256 + co);
        }
#pragma unroll
        for (int mt = 0; mt < 4; ++mt)
#pragma unroll
            for (int nt = 0; nt < 4; ++nt)
                acc[mt][nt] = __builtin_amdgcn_mfma_f32_16x16x32_bf16(a[mt], bfr[nt], acc[mt][nt], 0, 0, 0);
    }

    // --- Epilogue: D layout col=lane&15, row=quad*4+reg ---
    float* outg = out + (size_t)g * HW * HW;
#pragma unroll
    for (int mt = 0; mt < 4; ++mt) {
#pragma unroll
        for (int rr = 0; rr < 4; ++rr) {
            int row = p0 + wp + mt * 16 + quad * 4 + rr;
            float* orow = outg + (size_t)row * HW + q0 + wq + lr;
#pragma unroll
            for (int nt = 0; nt < 4; ++nt)
                orow[nt * 16] = acc[mt][nt][rr];   // 64B contiguous per quarter-wave
        }
    }
}

extern "C" void kernel_launch(void* const* d_in, const int* in_sizes, int n_in,
                              void* d_out, int out_size, void* d_ws, size_t ws_size,
                              hipStream_t stream) {
    const float* x = (const float*)d_in[0];
    float* out = (float*)d_out;
    __hip_bfloat16* fnT = (__hip_bfloat16*)d_ws;   // 32*1024*128*2 = 8 MB

    norm_transpose<<<dim3(32 * 1024 / 256), 256, 0, stream>>>(x, fnT);
    corr_gemm<<<dim3(8, 8, 96), 256, 0, stream>>>(fnT, out);
}